// Round 5
// baseline (277.302 us; speedup 1.0000x reference)
//
#include <hip/hip_runtime.h>
#include <math.h>

#define N_NODES 512
#define NE      4096
#define H       128
#define HH      1024
#define RBFK    64
#define KCAT    576   // 128 (ai) + 384 (eij) + 64 (rbf)
#define ALPHA   0.08838834764831845f
#define TPAD    64    // padded per-tgt edge list (max seg ~25 for random 4096->512)

typedef __attribute__((ext_vector_type(8))) short bf16x8;
typedef __attribute__((ext_vector_type(4))) float f32x4;
typedef __attribute__((ext_vector_type(4))) short short4v;

__device__ __forceinline__ short f2bf(float x) {
    unsigned u = __builtin_bit_cast(unsigned, x);
    unsigned r = u + 0x7FFFu + ((u >> 16) & 1u);   // RNE
    return (short)(r >> 16);
}
__device__ __forceinline__ float bf2f(short s) {
    return __builtin_bit_cast(float, ((unsigned)(unsigned short)s) << 16);
}

__device__ __forceinline__ void gload16(const short* g, short* l) {
    __builtin_amdgcn_global_load_lds(
        (const __attribute__((address_space(1))) void*)g,
        (__attribute__((address_space(3))) void*)l, 16, 0, 0);
}

// ---------------- D1: prep (sort fully parallelized into edge section) ----------------
// No serial sort block. Edge section computes, via global atomics:
//   cntS/cntT histograms, rankIn[p] (rank within src segment),
//   idxTP[tg*TPAD+pos]=p (tgt-grouped padded lists), srcO/tgtO decode.
// Scans + finalize (segStart/segStartT/nseg/rankS/idxT) run as ONE extra
// block inside k_big (hidden under its GEMM blocks).
#define RA 524288      // NE*H edge features
#define RB 589824      // BcatT 576*1024
#define RBZ 65536      // BcatT zero rows 576..639
#define RW 262144      // WqkT 2048*128
#define RCW 2048       // cwq+cwk colsums
#define RD 131072      // olT
#define RE 32768       // liT+ljT
#define RG 65536       // embB 512*128
#define RF 512         // cvec4 partials (4 chunks x 128, race-free)
#define RTOT (RA+RB+RBZ+RW+RCW+RD+RE+RG+RF)   // 1,673,728 = 6538*256

__global__ __launch_bounds__(256) void k_prep(
    const int* __restrict__ ei, const float* __restrict__ ew,
    const float* __restrict__ atom_embs, const float* __restrict__ pos,
    const float* __restrict__ Wq, const float* __restrict__ Wk, const float* __restrict__ Wv,
    const float* __restrict__ li_w, const float* __restrict__ lj_w,
    const float* __restrict__ el_w, const float* __restrict__ rl_w,
    const float* __restrict__ ol_w, const float* __restrict__ el_b, const float* __restrict__ rl_b,
    int* __restrict__ srcO, int* __restrict__ tgtO, int* __restrict__ rankIn,
    int* __restrict__ cntS, int* __restrict__ cntT, int* __restrict__ idxTP,
    short* __restrict__ Acat, short* __restrict__ ajB, short* __restrict__ BcatT,
    short* __restrict__ WqkT, float* __restrict__ cwq, float* __restrict__ cwk,
    short* __restrict__ olT, short* __restrict__ liT, short* __restrict__ ljT,
    short* __restrict__ embB, float* __restrict__ cvec4)
{
    __shared__ int flag;
    const int t = threadIdx.x;
    if (t < 64) {
        int vv = ei[2 * t + 1];
        unsigned long long m = __ballot(vv != 0);
        if (t == 0) flag = (m == 0ULL);
    }
    __syncthreads();
    const int is64 = flag;

    int idx = blockIdx.x * 256 + t;
    if (idx < RA) {                       // edge features (orig order)
        int p = idx >> 7, h = idx & 127;
        int s  = is64 ? ei[2 * p]          : ei[p];
        int tg = is64 ? ei[2 * NE + 2 * p] : ei[NE + p];
        float w = ew[p];
        Acat[(size_t)p * KCAT + h] = f2bf(atom_embs[tg * H + h] + w);
        ajB[idx] = f2bf(atom_embs[s * H + h] + w);
        if (h == 0) {
            srcO[p] = s; tgtO[p] = tg;
            rankIn[p] = atomicAdd(&cntS[s], 1);
            int posq = atomicAdd(&cntT[tg], 1);
            if (posq < TPAD) idxTP[tg * TPAD + posq] = p;
        }
        if (h < RBFK) {
            float dx = pos[tg * 3 + 0] - pos[s * 3 + 0];
            float dy = pos[tg * 3 + 1] - pos[s * 3 + 1];
            float dz = pos[tg * 3 + 2] - pos[s * 3 + 2];
            float d = sqrtf(dx * dx + dy * dy + dz * dz);
            float x = d * 0.1f;
            float cut = 0.0f;
            if (x < 1.0f) {
                float x3 = x * x * x, x4 = x3 * x, x5 = x4 * x;
                cut = 1.0f - 6.0f * x5 + 15.0f * x4 - 10.0f * x3;
            }
            float ck = 1.0f + (float)h * (-0.015872295239210119f);
            float tt = expf(-d) - ck;
            Acat[(size_t)p * KCAT + 512 + h] = f2bf(cut * expf(-1024.0929857f * tt * tt));
        }
        return;
    }
    idx -= RA;
    if (idx < RB) {                       // BcatT rows: [Wv; el_w; rl_w]
        int k = idx >> 10, n = idx & 1023;
        float v = (k < 128) ? Wv[k * HH + n]
                : (k < 512) ? el_w[(k - 128) * HH + n]
                            : rl_w[(k - 512) * HH + n];
        BcatT[idx] = f2bf(v);
        return;
    }
    idx -= RB;
    if (idx < RBZ) { BcatT[RB + idx] = 0; return; }
    idx -= RBZ;
    if (idx < RW) {                       // WqkT [2048 x 128]
        int n = idx >> 7, k = idx & 127;
        float v = (n < 1024) ? Wq[k * HH + n] : Wk[k * HH + (n - 1024)];
        WqkT[idx] = f2bf(v);
        return;
    }
    idx -= RW;
    if (idx < RCW) {                      // cwq/cwk column sums
        int which = idx >> 10, j = idx & 1023;
        const float* W = which ? Wk : Wq;
        float s = 0.0f;
        for (int k = 0; k < H; k++) s += W[k * HH + j];
        (which ? cwk : cwq)[j] = s;
        return;
    }
    idx -= RCW;
    if (idx < RD) {                       // olT [128 x 1024]
        int h = idx >> 10, n = idx & 1023;
        olT[idx] = f2bf(ol_w[n * H + h]);
        return;
    }
    idx -= RD;
    if (idx < RE) {                       // liT / ljT
        int which = idx >> 14, r = idx & 16383;
        int n = r >> 7, k = r & 127;
        (which ? ljT : liT)[r] = f2bf((which ? lj_w : li_w)[k * H + n]);
        return;
    }
    idx -= RE;
    if (idx < RG) { embB[idx] = f2bf(atom_embs[idx]); return; }
    idx -= RG;
    {                                     // cvec4 partials: 4 chunks x 128 h
        int h = idx & 127, chunk = idx >> 7;
        float acc = 0.0f;
        int n0 = chunk * 256;
        for (int n = n0; n < n0 + 256; n++)
            acc += (el_b[n] + rl_b[n]) * ol_w[n * H + h];
        cvec4[idx] = acc;
    }
}

// ---------------- shared MFMA NT GEMM body (256 threads) ----------------
// out_mode: 0 = f32 (offset zoff_pitch), 1 = bf16, 3 = bf16 transposed
__device__ __forceinline__ void gemm_body(
    short* As, short* Bs,
    const short* __restrict__ A, int lda,
    const short* __restrict__ B, int ldb,
    void* __restrict__ Cp, int ldc,
    int kbeg, int kend, float alpha, const float* __restrict__ bias,
    long zoff_pitch, int out_mode, int row0, int col0)
{
    const int tid = threadIdx.x;
    const int wave = tid >> 6, lane = tid & 63;

    f32x4 acc[4][4];
#pragma unroll
    for (int i = 0; i < 4; i++)
#pragma unroll
        for (int j = 0; j < 4; j++) acc[i][j] = (f32x4){0.f, 0.f, 0.f, 0.f};

    const int m0 = (wave >> 1) * 64, n0 = (wave & 1) * 64;
    const int lr = lane >> 3;
    const int lc = (lane & 7) * 8;
    const int cl = lane & 15, quad = lane >> 4;

    for (int k0 = kbeg; k0 < kend; k0 += 64) {
#pragma unroll
        for (int i = 0; i < 4; i++) {
            int r = wave * 32 + i * 8;
            gload16(A + (size_t)(row0 + r + lr) * lda + k0 + lc, As + r * 64);
            gload16(B + (size_t)(col0 + r + lr) * ldb + k0 + lc, Bs + r * 64);
        }
        __syncthreads();
#pragma unroll
        for (int kk = 0; kk < 64; kk += 32) {
            bf16x8 af[4], bf[4];
            int ko = kk + quad * 8;
#pragma unroll
            for (int i = 0; i < 4; i++)
                af[i] = *(const bf16x8*)(As + (m0 + i * 16 + cl) * 64 + ko);
#pragma unroll
            for (int j = 0; j < 4; j++)
                bf[j] = *(const bf16x8*)(Bs + (n0 + j * 16 + cl) * 64 + ko);
#pragma unroll
            for (int i = 0; i < 4; i++)
#pragma unroll
                for (int j = 0; j < 4; j++)
                    acc[i][j] = __builtin_amdgcn_mfma_f32_16x16x32_bf16(af[i], bf[j], acc[i][j], 0, 0, 0);
        }
        __syncthreads();
    }

    if (out_mode == 1) {
        short* C = (short*)Cp;
#pragma unroll
        for (int i = 0; i < 4; i++)
#pragma unroll
            for (int j = 0; j < 4; j++) {
                int cc = col0 + n0 + j * 16 + cl;
                float bv = bias ? bias[cc] : 0.0f;
#pragma unroll
                for (int reg = 0; reg < 4; reg++) {
                    int rr = row0 + m0 + i * 16 + quad * 4 + reg;
                    C[(size_t)rr * ldc + cc] = f2bf(acc[i][j][reg] * alpha + bv);
                }
            }
    } else if (out_mode == 3) {
        short* C = (short*)Cp;
#pragma unroll
        for (int i = 0; i < 4; i++)
#pragma unroll
            for (int j = 0; j < 4; j++) {
                int cc = col0 + n0 + j * 16 + cl;
                int rr = row0 + m0 + i * 16 + quad * 4;
                short4v pack;
#pragma unroll
                for (int reg = 0; reg < 4; reg++) pack[reg] = f2bf(acc[i][j][reg] * alpha);
                *(short4v*)(C + (size_t)cc * ldc + rr) = pack;
            }
    } else {
        float* C = (float*)Cp + zoff_pitch;
#pragma unroll
        for (int i = 0; i < 4; i++)
#pragma unroll
            for (int j = 0; j < 4; j++) {
                int cc = col0 + n0 + j * 16 + cl;
#pragma unroll
                for (int reg = 0; reg < 4; reg++) {
                    int rr = row0 + m0 + i * 16 + quad * 4 + reg;
                    C[(size_t)rr * ldc + cc] = acc[i][j][reg] * alpha;
                }
            }
    }
}

__global__ __launch_bounds__(256) void k_gemm(
    const short* __restrict__ A, int lda,
    const short* __restrict__ B, int ldb,
    void* __restrict__ Cp, int ldc,
    int K, float alpha, const float* __restrict__ bias,
    long split_pitch, int out_mode)
{
    __shared__ __align__(16) short As[128 * 64];
    __shared__ __align__(16) short Bs[128 * 64];
    int kchunk = K / gridDim.z;
    gemm_body(As, Bs, A, lda, B, ldb, Cp, ldc,
              kchunk * blockIdx.z, kchunk * (blockIdx.z + 1), alpha, bias,
              (long)blockIdx.z * split_pitch, out_mode,
              blockIdx.y * 128, blockIdx.x * 128);
}

// ---------------- edgefeat body (device) ----------------
__device__ __forceinline__ void edgefeat_body(
    short* As, short* Bs, int row0,
    const short* __restrict__ Acat_in, const short* __restrict__ ajB,
    const short* __restrict__ liT, const short* __restrict__ ljT,
    const float* __restrict__ li_b, const float* __restrict__ lj_b,
    short* __restrict__ Acat)
{
    const int tid = threadIdx.x;
    const int wave = tid >> 6, lane = tid & 63;
    const int cl = lane & 15, quad = lane >> 4;
    const int m0 = (wave >> 1) * 64, n0 = (wave & 1) * 64;
    const int sr = lane >> 4, sc = (lane & 15) * 8;

    f32x4 ai_acc[4][4], aj_acc[4][4];
#pragma unroll
    for (int i = 0; i < 4; i++)
#pragma unroll
        for (int j = 0; j < 4; j++) {
            ai_acc[i][j] = (f32x4){0.f, 0.f, 0.f, 0.f};
            aj_acc[i][j] = (f32x4){0.f, 0.f, 0.f, 0.f};
        }

#pragma unroll
    for (int i = 0; i < 8; i++) {
        int r = wave * 32 + i * 4;
        gload16(Acat_in + (size_t)(row0 + r + sr) * KCAT + sc, As + r * 128);
        gload16(liT + (r + sr) * 128 + sc, Bs + r * 128);
    }
    __syncthreads();
#pragma unroll
    for (int kk = 0; kk < 128; kk += 32) {
        bf16x8 af[4], bf[4];
        int ko = kk + quad * 8;
#pragma unroll
        for (int i = 0; i < 4; i++) af[i] = *(const bf16x8*)(As + (m0 + i * 16 + cl) * 128 + ko);
#pragma unroll
        for (int j = 0; j < 4; j++) bf[j] = *(const bf16x8*)(Bs + (n0 + j * 16 + cl) * 128 + ko);
#pragma unroll
        for (int i = 0; i < 4; i++)
#pragma unroll
            for (int j = 0; j < 4; j++)
                ai_acc[i][j] = __builtin_amdgcn_mfma_f32_16x16x32_bf16(af[i], bf[j], ai_acc[i][j], 0, 0, 0);
    }
    __syncthreads();
#pragma unroll
    for (int i = 0; i < 8; i++) {
        int r = wave * 32 + i * 4;
        gload16(ajB + (size_t)(row0 + r + sr) * 128 + sc, As + r * 128);
        gload16(ljT + (r + sr) * 128 + sc, Bs + r * 128);
    }
    __syncthreads();
#pragma unroll
    for (int kk = 0; kk < 128; kk += 32) {
        bf16x8 af[4], bf[4];
        int ko = kk + quad * 8;
#pragma unroll
        for (int i = 0; i < 4; i++) af[i] = *(const bf16x8*)(As + (m0 + i * 16 + cl) * 128 + ko);
#pragma unroll
        for (int j = 0; j < 4; j++) bf[j] = *(const bf16x8*)(Bs + (n0 + j * 16 + cl) * 128 + ko);
#pragma unroll
        for (int i = 0; i < 4; i++)
#pragma unroll
            for (int j = 0; j < 4; j++)
                aj_acc[i][j] = __builtin_amdgcn_mfma_f32_16x16x32_bf16(af[i], bf[j], aj_acc[i][j], 0, 0, 0);
    }
#pragma unroll
    for (int i = 0; i < 4; i++)
#pragma unroll
        for (int j = 0; j < 4; j++) {
            int cc = n0 + j * 16 + cl;
            float bi = li_b[cc], bj = lj_b[cc];
#pragma unroll
            for (int reg = 0; reg < 4; reg++) {
                int rr = row0 + m0 + i * 16 + quad * 4 + reg;
                float hv = ai_acc[i][j][reg] + bi;
                float gv = aj_acc[i][j][reg] + bj;
                short* rowp = Acat + (size_t)rr * KCAT;
                rowp[128 + cc] = f2bf(hv + gv);
                rowp[256 + cc] = f2bf(hv - gv);
                rowp[384 + cc] = f2bf(hv * gv);
            }
        }
}

// ---------------- D2: edgefeat(32) + QK'(64) + W2T(5) + sortfin(1) ----------------
__global__ __launch_bounds__(256) void k_big(
    const short* __restrict__ Acat_in, const short* __restrict__ ajB,
    const short* __restrict__ liT, const short* __restrict__ ljT,
    const float* __restrict__ li_b, const float* __restrict__ lj_b,
    short* __restrict__ Acat,
    const short* __restrict__ embB, const short* __restrict__ WqkT,
    short* __restrict__ QKB,
    const short* __restrict__ olT, const short* __restrict__ BcatT,
    short* __restrict__ W2T,
    const int* __restrict__ cntS, const int* __restrict__ cntT,
    const int* __restrict__ srcO, const int* __restrict__ rankIn,
    const int* __restrict__ idxTP,
    int* __restrict__ segStart, int* __restrict__ segStartT,
    int* __restrict__ rankS, int* __restrict__ idxT, int* __restrict__ nsegp)
{
    __shared__ __align__(16) char smem[65536];
    if (blockIdx.x < 32) {
        edgefeat_body((short*)smem, (short*)(smem + 32768), blockIdx.x * 128,
                      Acat_in, ajB, liT, ljT, li_b, lj_b, Acat);
    } else if (blockIdx.x < 96) {
        int id = blockIdx.x - 32;
        gemm_body((short*)smem, (short*)(smem + 16384),
                  embB, H, WqkT, H, QKB, 2048, 0, H, 1.0f, nullptr, 0, 1,
                  (id >> 4) * 128, (id & 15) * 128);
    } else if (blockIdx.x < 101) {
        int id = blockIdx.x - 96;
        gemm_body((short*)smem, (short*)(smem + 16384),
                  olT, HH, BcatT, HH, W2T, 640, 0, HH, 1.0f, nullptr, 0, 1,
                  0, id * 128);
    } else {
        // sort finalize: dual scan + nseg + rankS + idxT compaction (~5 us)
        int* sS = (int*)smem;            // 512 ints
        int* sT = sS + 512;              // 512 ints
        int* red = sT + 512;             // 256 ints
        const int t = threadIdx.x;
        sS[t] = cntS[t]; sS[t + 256] = cntS[t + 256];
        sT[t] = cntT[t]; sT[t + 256] = cntT[t + 256];
        __syncthreads();
        for (int off = 1; off < 512; off <<= 1) {
            int i2 = t + 256;
            int a1 = (t >= off) ? sS[t - off] : 0;
            int b1 = (t >= off) ? sT[t - off] : 0;
            int a2 = sS[i2 - off];
            int b2 = sT[i2 - off];
            __syncthreads();
            sS[t] += a1; sT[t] += b1;
            sS[i2] += a2; sT[i2] += b2;
            __syncthreads();
        }
        segStart[t + 1]    = sS[t];
        segStart[t + 257]  = sS[t + 256];
        segStartT[t + 1]   = sT[t];
        segStartT[t + 257] = sT[t + 256];
        if (t == 0) { segStart[0] = 0; segStartT[0] = 0; }
        red[t] = (cntS[t] > 0) + (cntS[t + 256] > 0);
        __syncthreads();
        for (int off = 128; off > 0; off >>= 1) {
            if (t < off) red[t] += red[t + off];
            __syncthreads();
        }
        if (t == 0) nsegp[0] = red[0];
        // rankS[e] = exclusive_start(src) + rankIn[e]
        for (int e = t; e < NE; e += 256) {
            int s = srcO[e];
            rankS[e] = (sS[s] - cntS[s]) + rankIn[e];
        }
        // idxT compaction from padded per-tgt lists
        for (int n = t; n < N_NODES; n += 256) {
            int c = cntT[n];
            int base = sT[n] - c;
            const int* srcp = idxTP + n * TPAD;
            for (int j = 0; j < c; j++) idxT[base + j] = srcp[j];
        }
    }
}

// ---------------- D3: Z split-K (32) + GT(32) + wave-parallel p/q/s (16) ----------------
__global__ __launch_bounds__(256) void k_zr(
    const short* __restrict__ QKB,
    const float* __restrict__ cwq, const float* __restrict__ cwk,
    const short* __restrict__ Acat, const short* __restrict__ W2T,
    short* __restrict__ GT,
    float* __restrict__ Z, float* __restrict__ pv, float* __restrict__ qv,
    float* __restrict__ sv)
{
    __shared__ __align__(16) char smem[32768];
    if (blockIdx.x < 32) {
        // Z = Q@K' split into 2 K-slices
        int zs = blockIdx.x >> 4;       // K slice 0/1
        int tile = blockIdx.x & 15;
        gemm_body((short*)smem, (short*)(smem + 16384),
                  QKB, 2048, QKB + 1024, 2048, Z, N_NODES,
                  zs * 512, zs * 512 + 512, ALPHA, nullptr,
                  (long)zs * ((long)N_NODES * N_NODES), 0,
                  (tile >> 2) * 128, (tile & 3) * 128);
    } else if (blockIdx.x < 64) {
        int id = blockIdx.x - 32;
        gemm_body((short*)smem, (short*)(smem + 16384),
                  Acat, KCAT, W2T, 640, GT, NE, 0, KCAT, 1.0f, nullptr, 0, 3,
                  id * 128, 0);
    } else {
        int b = blockIdx.x - 64;
        int t = threadIdx.x;
        int wave = t >> 6, lane = t & 63;
        if (b == 0 && wave == 0) {
            float a = 0.0f;
            for (int j = lane; j < HH; j += 64) a += cwq[j] * cwk[j];
            for (int off = 32; off > 0; off >>= 1) a += __shfl_down(a, off);
            if (lane == 0) sv[0] = a;
        }
        for (int ni = 0; ni < 8; ni++) {
            int n = b * 32 + wave * 8 + ni;
            const short* qr = QKB + (size_t)n * 2048;
            float pa = 0.0f, qa = 0.0f;
            int j0 = lane * 16;
#pragma unroll
            for (int j = 0; j < 16; j++) {
                pa += bf2f(qr[j0 + j]) * cwk[j0 + j];
                qa += bf2f(qr[1024 + j0 + j]) * cwq[j0 + j];
            }
            for (int off = 32; off > 0; off >>= 1) {
                pa += __shfl_down(pa, off);
                qa += __shfl_down(qa, off);
            }
            if (lane == 0) { pv[n] = pa; qv[n] = qa; }
        }
    }
}

// ---------------- D4 denom (orig-edge rows) ----------------
// l[r,c] = (Z[tr,tc] + α·er·q[tc]) + ec·β,  β = α·(p_tr + er·s)
// row[] scattered by rankS so segment sums read contiguous LDS ranges.
__global__ __launch_bounds__(512) void k_denom(
    const float* __restrict__ Z, const float* __restrict__ pv,
    const float* __restrict__ qv, const float* __restrict__ sv,
    const int* __restrict__ tgtO, const float* __restrict__ ew,
    const int* __restrict__ rankS,
    const int* __restrict__ segStart, float* __restrict__ rDen)
{
    __shared__ float row[NE];        // 16 KB
    __shared__ float zq[N_NODES];    // 2 KB
    const int r = blockIdx.x, t = threadIdx.x;
    const int tr = tgtO[r];
    const float er = ew[r];
    const float aer = ALPHA * er;
    for (int i = t; i < N_NODES; i += 512)
        zq[i] = Z[(size_t)tr * N_NODES + i]
              + Z[(size_t)N_NODES * N_NODES + (size_t)tr * N_NODES + i]
              + aer * qv[i];
    __syncthreads();
    const float beta = ALPHA * (pv[tr] + er * sv[0]);
    for (int c = t; c < NE; c += 512)
        row[rankS[c]] = __expf(zq[tgtO[c]] + ew[c] * beta);
    __syncthreads();
    float* rd = rDen + (size_t)r * N_NODES;
    if (t < N_NODES) {
        int a = segStart[t], b = segStart[t + 1];
        float s = 0.0f;
        for (int p = a; p < b; p++) s += row[p];
        rd[t] = (s > 0.0f) ? 1.0f / s : 0.0f;
    }
}

// ---------------- D5 Pagg (orig-edge columns) ----------------
__global__ __launch_bounds__(256) void k_pagg2(
    const float* __restrict__ Z, const float* __restrict__ pv,
    const float* __restrict__ qv, const float* __restrict__ sv,
    const float* __restrict__ rDen,
    const int* __restrict__ tgtO, const float* __restrict__ ew,
    const int* __restrict__ srcO, const int* __restrict__ segStartT,
    const int* __restrict__ idxT, short* __restrict__ PaggB)
{
    __shared__ float zrow[N_NODES];   // 2 KB
    __shared__ float aq[N_NODES];     // 2 KB (alpha * q)
    __shared__ float erL[32];
    __shared__ int   eL[32];
    const int n = blockIdx.y;
    const int c0 = blockIdx.x * 1024;
    const int t = threadIdx.x;
    for (int i = t; i < N_NODES; i += 256) {
        zrow[i] = Z[(size_t)n * N_NODES + i]
                + Z[(size_t)N_NODES * N_NODES + (size_t)n * N_NODES + i];
        aq[i]   = ALPHA * qv[i];
    }
    __syncthreads();
    const float p_n = pv[n];
    const float s = sv[0];
    float A4[4], cB4[4];
    int sc4[4];
#pragma unroll
    for (int q = 0; q < 4; q++) {
        int c = c0 + t + q * 256;
        int tc = tgtO[c]; float ec = ew[c];
        A4[q]  = zrow[tc] + (ALPHA * ec) * p_n;
        cB4[q] = aq[tc] + (ALPHA * ec) * s;
        sc4[q] = srcO[c];
    }
    float acc[4] = {0.f, 0.f, 0.f, 0.f};
    const int a = segStartT[n], b = segStartT[n + 1];
    for (int ch = a; ch < b; ch += 32) {
        int ne = b - ch; if (ne > 32) ne = 32;
        __syncthreads();
        if (t < ne) { int e = idxT[ch + t]; eL[t] = e; erL[t] = ew[e]; }
        __syncthreads();
        for (int k = 0; k < ne; k++) {
            const float er = erL[k];
            const float* rde = rDen + (size_t)eL[k] * N_NODES;
#pragma unroll
            for (int q = 0; q < 4; q++)
                acc[q] += __expf(A4[q] + er * cB4[q]) * rde[sc4[q]];
        }
    }
    short* pr = PaggB + (size_t)n * NE + c0;
#pragma unroll
    for (int q = 0; q < 4; q++)
        pr[t + q * 256] = f2bf(acc[q]);
}

// ---------------- D7 head: sum 8 agg partials + LN + FFN + LN ----------------
__global__ __launch_bounds__(128) void k_head(
    const float* __restrict__ aggP, const int* __restrict__ segStartT,
    const int* __restrict__ nsegp,
    const float* __restrict__ cvec4, const float* __restrict__ ol_b,
    const float* __restrict__ ln_g, const float* __restrict__ ln_b,
    const float* __restrict__ f1_w, const float* __restrict__ f1_b,
    const float* __restrict__ f2_w, const float* __restrict__ f2_b,
    const float* __restrict__ f3_w, const float* __restrict__ f3_b,
    float* __restrict__ out)
{
    __shared__ float x[H];
    __shared__ float red[H];
    int t = threadIdx.x, row = blockIdx.x;
    int cnt = segStartT[row + 1] - segStartT[row];
    float cv = cvec4[t] + cvec4[128 + t] + cvec4[256 + t] + cvec4[384 + t];
    float v = (float)cnt * (ol_b[t] + (float)nsegp[0] * cv);
    const float* ap = aggP + (size_t)row * H + t;
#pragma unroll
    for (int z = 0; z < 8; z++) v += ap[(size_t)z * N_NODES * H];
    red[t] = v; __syncthreads();
    for (int s = 64; s > 0; s >>= 1) { if (t < s) red[t] += red[t + s]; __syncthreads(); }
    float mu = red[0] * (1.0f / H); __syncthreads();
    float dv = v - mu;
    red[t] = dv * dv; __syncthreads();
    for (int s = 64; s > 0; s >>= 1) { if (t < s) red[t] += red[t + s]; __syncthreads(); }
    float var = red[0] * (1.0f / H); __syncthreads();
    x[t] = dv * rsqrtf(var + 1e-5f) * ln_g[t] + ln_b[t];
    __syncthreads();
    const float* Ws[3] = { f1_w, f2_w, f3_w };
    const float* Bb[3] = { f1_b, f2_b, f3_b };
    for (int l = 0; l < 3; l++) {
        float acc = Bb[l][t];
        const float* Wl = Ws[l];
        for (int k = 0; k < H; k++) acc = fmaf(x[k], Wl[k * H + t], acc);
        float o = fmaxf(acc, 0.0f) + log1pf(expf(-fabsf(acc)));
        __syncthreads();
        x[t] = o;
        __syncthreads();
    }
    float xv = x[t];
    red[t] = xv; __syncthreads();
    for (int s = 64; s > 0; s >>= 1) { if (t < s) red[t] += red[t + s]; __syncthreads(); }
    mu = red[0] * (1.0f / H); __syncthreads();
    float dv2 = xv - mu;
    red[t] = dv2 * dv2; __syncthreads();
    for (int s = 64; s > 0; s >>= 1) { if (t < s) red[t] += red[t + s]; __syncthreads(); }
    var = red[0] * (1.0f / H);
    out[row * H + t] = dv2 * rsqrtf(var + 1e-5f) * ln_g[t] + ln_b[t];
}

// ---------------- launch ----------------

extern "C" void kernel_launch(void* const* d_in, const int* in_sizes, int n_in,
                              void* d_out, int out_size, void* d_ws, size_t ws_size,
                              hipStream_t stream) {
    const float* atom_embs   = (const float*)d_in[0];
    const float* pos         = (const float*)d_in[1];
    const float* edge_weight = (const float*)d_in[2];
    const int*   edge_idx    = (const int*)d_in[3];
    const float* Wq   = (const float*)d_in[4];
    const float* Wk   = (const float*)d_in[5];
    const float* Wv   = (const float*)d_in[6];
    const float* li_w = (const float*)d_in[7];
    const float* li_b = (const float*)d_in[8];
    const float* lj_w = (const float*)d_in[9];
    const float* lj_b = (const float*)d_in[10];
    const float* el_w = (const float*)d_in[11];
    const float* el_b = (const float*)d_in[12];
    const float* rl_w = (const float*)d_in[13];
    const float* rl_b = (const float*)d_in[14];
    const float* ol_w = (const float*)d_in[15];
    const float* ol_b = (const float*)d_in[16];
    const float* ln_g = (const float*)d_in[17];
    const float* ln_b = (const float*)d_in[18];
    const float* f1_w = (const float*)d_in[19];
    const float* f1_b = (const float*)d_in[20];
    const float* f2_w = (const float*)d_in[21];
    const float* f2_b = (const float*)d_in[22];
    const float* f3_w = (const float*)d_in[23];
    const float* f3_b = (const float*)d_in[24];
    float* out = (float*)d_out;

    char* w = (char*)d_ws;
    size_t off = 0;
    auto alloc = [&](size_t bytes) -> void* {
        void* p = w + off;
        off += (bytes + 255) & ~(size_t)255;
        return p;
    };
    int*   cntS      = (int*)alloc(2 * N_NODES * 4);   // cntS[512] + cntT[512], one memset
    int*   cntT      = cntS + N_NODES;
    int*   srcO      = (int*)alloc(NE * 4);
    int*   tgtO      = (int*)alloc(NE * 4);
    int*   rankIn    = (int*)alloc(NE * 4);
    int*   rankS     = (int*)alloc(NE * 4);
    int*   idxT      = (int*)alloc(NE * 4);
    int*   idxTP     = (int*)alloc((size_t)N_NODES * TPAD * 4);
    int*   segStart  = (int*)alloc((N_NODES + 1) * 4);
    int*   segStartT = (int*)alloc((N_NODES + 1) * 4);
    int*   nsegp     = (int*)alloc(4);
    short* Acat   = (short*)alloc((size_t)NE * KCAT * 2);
    short* ajB    = (short*)alloc((size_t)NE * H * 2);
    short* BcatT  = (short*)alloc((size_t)640 * HH * 2);
    short* WqkT   = (short*)alloc((size_t)2048 * H * 2);
    float* cwq    = (float*)alloc(HH * 4);
    float* cwk    = (float*)alloc(HH * 4);
    short* olT    = (short*)alloc((size_t)H * HH * 2);
    short* liT    = (short*)alloc((size_t)H * H * 2);
    short* ljT    = (short*)alloc((size_t)H * H * 2);
    short* embB   = (short*)alloc((size_t)N_NODES * H * 2);
    float* cvec4  = (float*)alloc(512 * 4);
    short* W2T    = (short*)alloc((size_t)H * 640 * 2);
    short* QKB    = (short*)alloc((size_t)N_NODES * 2048 * 2);
    float* Z      = (float*)alloc((size_t)2 * N_NODES * N_NODES * 4);  // 2 K-slices
    float* pv     = (float*)alloc(N_NODES * 4);
    float* qv     = (float*)alloc(N_NODES * 4);
    float* sv     = (float*)alloc(4);
    short* GT     = (short*)alloc((size_t)H * NE * 2);
    float* rDen   = (float*)alloc((size_t)NE * N_NODES * 4);
    short* PaggB  = (short*)alloc((size_t)N_NODES * NE * 2);
    float* aggP   = (float*)alloc((size_t)8 * N_NODES * H * 4);

    // D0: zero the atomic counters (4 KB)
    hipMemsetAsync(cntS, 0, 2 * N_NODES * 4, stream);
    // D1: prep (fully parallel; sort histograms via global atomics)
    k_prep<<<RTOT / 256, 256, 0, stream>>>(
        edge_idx, edge_weight, atom_embs, pos,
        Wq, Wk, Wv, li_w, lj_w, el_w, rl_w, ol_w, el_b, rl_b,
        srcO, tgtO, rankIn, cntS, cntT, idxTP,
        Acat, ajB, BcatT, WqkT, cwq, cwk, olT, liT, ljT, embB, cvec4);
    // D2: edgefeat + QK' + W2T + sort-finalize block
    k_big<<<102, 256, 0, stream>>>(Acat, ajB, liT, ljT, li_b, lj_b, Acat,
                                   embB, WqkT, QKB, olT, BcatT, W2T,
                                   cntS, cntT, srcO, rankIn, idxTP,
                                   segStart, segStartT, rankS, idxT, nsegp);
    // D3: Z (split-K=2) + GT + wave-parallel p/q/s
    k_zr<<<80, 256, 0, stream>>>(QKB, cwq, cwk, Acat, W2T, GT, Z, pv, qv, sv);
    // D4: denominators (edge-parallel, 4096 blocks)
    k_denom<<<NE, 512, 0, stream>>>(Z, pv, qv, sv, tgtO, edge_weight, rankS,
                                    segStart, rDen);
    // D5: Pagg
    {
        dim3 g(4, N_NODES);
        k_pagg2<<<g, 256, 0, stream>>>(Z, pv, qv, sv, rDen, tgtO, edge_weight,
                                       srcO, segStartT, idxT, PaggB);
    }
    // D6: agg = Pagg @ G : split-K=8
    {
        dim3 g(1, N_NODES / 128, 8);
        k_gemm<<<g, 256, 0, stream>>>(PaggB, NE, GT, NE, aggP, H, NE, 1.0f, nullptr,
                                      (long)N_NODES * H, 0);
    }
    // D7: head
    k_head<<<N_NODES, 128, 0, stream>>>(aggP, segStartT, nsegp, cvec4, ol_b,
                                        ln_g, ln_b, f1_w, f1_b, f2_w, f2_b, f3_w, f3_b, out);
}

// Round 6
// 217.606 us; speedup vs baseline: 1.2743x; 1.2743x over previous
//
#include <hip/hip_runtime.h>
#include <math.h>

#define N_NODES 512
#define NE      4096
#define H       128
#define HH      1024
#define RBFK    64
#define KCAT    576   // 128 (ai) + 384 (eij) + 64 (rbf)
#define ALPHA   0.08838834764831845f
#define TPAD    64    // padded per-tgt edge list (max seg ~25 for random 4096->512)

typedef __attribute__((ext_vector_type(8))) short bf16x8;
typedef __attribute__((ext_vector_type(4))) float f32x4;
typedef __attribute__((ext_vector_type(4))) short short4v;

__device__ __forceinline__ short f2bf(float x) {
    unsigned u = __builtin_bit_cast(unsigned, x);
    unsigned r = u + 0x7FFFu + ((u >> 16) & 1u);   // RNE
    return (short)(r >> 16);
}
__device__ __forceinline__ float bf2f(short s) {
    return __builtin_bit_cast(float, ((unsigned)(unsigned short)s) << 16);
}

__device__ __forceinline__ void gload16(const short* g, short* l) {
    __builtin_amdgcn_global_load_lds(
        (const __attribute__((address_space(1))) void*)g,
        (__attribute__((address_space(3))) void*)l, 16, 0, 0);
}

// ---------------- D1: prep (sort parallelized; NO long per-thread loops) ----------------
// Latency-tail rule (R5 lesson): grid-tail sections with few blocks and long
// dependent-load loops run alone at the end of the dispatch and dominate it.
// Keep per-thread trip counts <= 32.
#define RA 524288      // NE*H edge features
#define RB 589824      // BcatT 576*1024
#define RBZ 65536      // BcatT zero rows 576..639
#define RW 262144      // WqkT 2048*128
#define RCW 8192       // cw colsum partials: 2 (q/k) x 4 chunks x 1024, 32-iter loops
#define RD 131072      // olT
#define RE 32768       // liT+ljT
#define RG 65536       // embB 512*128
#define RF 4096        // cvec32 partials: 32 chunks x 128, 32-iter loops
#define RTOT (RA+RB+RBZ+RW+RCW+RD+RE+RG+RF)   // 1,683,456 = 6576*256

__global__ __launch_bounds__(256) void k_prep(
    const int* __restrict__ ei, const float* __restrict__ ew,
    const float* __restrict__ atom_embs, const float* __restrict__ pos,
    const float* __restrict__ Wq, const float* __restrict__ Wk, const float* __restrict__ Wv,
    const float* __restrict__ li_w, const float* __restrict__ lj_w,
    const float* __restrict__ el_w, const float* __restrict__ rl_w,
    const float* __restrict__ ol_w, const float* __restrict__ el_b, const float* __restrict__ rl_b,
    int* __restrict__ srcO, int* __restrict__ tgtO, int* __restrict__ rankIn,
    int* __restrict__ cntS, int* __restrict__ cntT, int* __restrict__ idxTP,
    short* __restrict__ Acat, short* __restrict__ ajB, short* __restrict__ BcatT,
    short* __restrict__ WqkT, float* __restrict__ cwq4, float* __restrict__ cwk4,
    short* __restrict__ olT, short* __restrict__ liT, short* __restrict__ ljT,
    short* __restrict__ embB, float* __restrict__ cvec32)
{
    __shared__ int flag;
    const int t = threadIdx.x;
    if (t < 64) {
        int vv = ei[2 * t + 1];
        unsigned long long m = __ballot(vv != 0);
        if (t == 0) flag = (m == 0ULL);
    }
    __syncthreads();
    const int is64 = flag;

    int idx = blockIdx.x * 256 + t;
    if (idx < RA) {                       // edge features (orig order)
        int p = idx >> 7, h = idx & 127;
        int s  = is64 ? ei[2 * p]          : ei[p];
        int tg = is64 ? ei[2 * NE + 2 * p] : ei[NE + p];
        float w = ew[p];
        Acat[(size_t)p * KCAT + h] = f2bf(atom_embs[tg * H + h] + w);
        ajB[idx] = f2bf(atom_embs[s * H + h] + w);
        if (h == 0) {
            srcO[p] = s; tgtO[p] = tg;
            rankIn[p] = atomicAdd(&cntS[s], 1);
            int posq = atomicAdd(&cntT[tg], 1);
            if (posq < TPAD) idxTP[tg * TPAD + posq] = p;
        }
        if (h < RBFK) {
            float dx = pos[tg * 3 + 0] - pos[s * 3 + 0];
            float dy = pos[tg * 3 + 1] - pos[s * 3 + 1];
            float dz = pos[tg * 3 + 2] - pos[s * 3 + 2];
            float d = sqrtf(dx * dx + dy * dy + dz * dz);
            float x = d * 0.1f;
            float cut = 0.0f;
            if (x < 1.0f) {
                float x3 = x * x * x, x4 = x3 * x, x5 = x4 * x;
                cut = 1.0f - 6.0f * x5 + 15.0f * x4 - 10.0f * x3;
            }
            float ck = 1.0f + (float)h * (-0.015872295239210119f);
            float tt = expf(-d) - ck;
            Acat[(size_t)p * KCAT + 512 + h] = f2bf(cut * expf(-1024.0929857f * tt * tt));
        }
        return;
    }
    idx -= RA;
    if (idx < RB) {                       // BcatT rows: [Wv; el_w; rl_w]
        int k = idx >> 10, n = idx & 1023;
        float v = (k < 128) ? Wv[k * HH + n]
                : (k < 512) ? el_w[(k - 128) * HH + n]
                            : rl_w[(k - 512) * HH + n];
        BcatT[idx] = f2bf(v);
        return;
    }
    idx -= RB;
    if (idx < RBZ) { BcatT[RB + idx] = 0; return; }
    idx -= RBZ;
    if (idx < RW) {                       // WqkT [2048 x 128]
        int n = idx >> 7, k = idx & 127;
        float v = (n < 1024) ? Wq[k * HH + n] : Wk[k * HH + (n - 1024)];
        WqkT[idx] = f2bf(v);
        return;
    }
    idx -= RW;
    if (idx < RCW) {                      // cw colsum partials (32-iter loops)
        int which = idx >> 12;            // 0=q, 1=k
        int chunk = (idx >> 10) & 3;
        int j = idx & 1023;
        const float* W = which ? Wk : Wq;
        float s = 0.0f;
        int k0 = chunk * 32;
#pragma unroll
        for (int k = k0; k < k0 + 32; k++) s += W[k * HH + j];
        (which ? cwk4 : cwq4)[chunk * 1024 + j] = s;
        return;
    }
    idx -= RCW;
    if (idx < RD) {                       // olT [128 x 1024]
        int h = idx >> 10, n = idx & 1023;
        olT[idx] = f2bf(ol_w[n * H + h]);
        return;
    }
    idx -= RD;
    if (idx < RE) {                       // liT / ljT
        int which = idx >> 14, r = idx & 16383;
        int n = r >> 7, k = r & 127;
        (which ? ljT : liT)[r] = f2bf((which ? lj_w : li_w)[k * H + n]);
        return;
    }
    idx -= RE;
    if (idx < RG) { embB[idx] = f2bf(atom_embs[idx]); return; }
    idx -= RG;
    {                                     // cvec32 partials: 32 chunks x 128 h (32-iter loops)
        int h = idx & 127, chunk = idx >> 7;
        float acc = 0.0f;
        int n0 = chunk * 32;
#pragma unroll
        for (int n = n0; n < n0 + 32; n++)
            acc += (el_b[n] + rl_b[n]) * ol_w[n * H + h];
        cvec32[idx] = acc;
    }
}

// ---------------- shared MFMA NT GEMM body (256 threads) ----------------
// out_mode: 0 = f32 (offset zoff_pitch), 1 = bf16, 3 = bf16 transposed
__device__ __forceinline__ void gemm_body(
    short* As, short* Bs,
    const short* __restrict__ A, int lda,
    const short* __restrict__ B, int ldb,
    void* __restrict__ Cp, int ldc,
    int kbeg, int kend, float alpha, const float* __restrict__ bias,
    long zoff_pitch, int out_mode, int row0, int col0)
{
    const int tid = threadIdx.x;
    const int wave = tid >> 6, lane = tid & 63;

    f32x4 acc[4][4];
#pragma unroll
    for (int i = 0; i < 4; i++)
#pragma unroll
        for (int j = 0; j < 4; j++) acc[i][j] = (f32x4){0.f, 0.f, 0.f, 0.f};

    const int m0 = (wave >> 1) * 64, n0 = (wave & 1) * 64;
    const int lr = lane >> 3;
    const int lc = (lane & 7) * 8;
    const int cl = lane & 15, quad = lane >> 4;

    for (int k0 = kbeg; k0 < kend; k0 += 64) {
#pragma unroll
        for (int i = 0; i < 4; i++) {
            int r = wave * 32 + i * 8;
            gload16(A + (size_t)(row0 + r + lr) * lda + k0 + lc, As + r * 64);
            gload16(B + (size_t)(col0 + r + lr) * ldb + k0 + lc, Bs + r * 64);
        }
        __syncthreads();
#pragma unroll
        for (int kk = 0; kk < 64; kk += 32) {
            bf16x8 af[4], bf[4];
            int ko = kk + quad * 8;
#pragma unroll
            for (int i = 0; i < 4; i++)
                af[i] = *(const bf16x8*)(As + (m0 + i * 16 + cl) * 64 + ko);
#pragma unroll
            for (int j = 0; j < 4; j++)
                bf[j] = *(const bf16x8*)(Bs + (n0 + j * 16 + cl) * 64 + ko);
#pragma unroll
            for (int i = 0; i < 4; i++)
#pragma unroll
                for (int j = 0; j < 4; j++)
                    acc[i][j] = __builtin_amdgcn_mfma_f32_16x16x32_bf16(af[i], bf[j], acc[i][j], 0, 0, 0);
        }
        __syncthreads();
    }

    if (out_mode == 1) {
        short* C = (short*)Cp;
#pragma unroll
        for (int i = 0; i < 4; i++)
#pragma unroll
            for (int j = 0; j < 4; j++) {
                int cc = col0 + n0 + j * 16 + cl;
                float bv = bias ? bias[cc] : 0.0f;
#pragma unroll
                for (int reg = 0; reg < 4; reg++) {
                    int rr = row0 + m0 + i * 16 + quad * 4 + reg;
                    C[(size_t)rr * ldc + cc] = f2bf(acc[i][j][reg] * alpha + bv);
                }
            }
    } else if (out_mode == 3) {
        short* C = (short*)Cp;
#pragma unroll
        for (int i = 0; i < 4; i++)
#pragma unroll
            for (int j = 0; j < 4; j++) {
                int cc = col0 + n0 + j * 16 + cl;
                int rr = row0 + m0 + i * 16 + quad * 4;
                short4v pack;
#pragma unroll
                for (int reg = 0; reg < 4; reg++) pack[reg] = f2bf(acc[i][j][reg] * alpha);
                *(short4v*)(C + (size_t)cc * ldc + rr) = pack;
            }
    } else {
        float* C = (float*)Cp + zoff_pitch;
#pragma unroll
        for (int i = 0; i < 4; i++)
#pragma unroll
            for (int j = 0; j < 4; j++) {
                int cc = col0 + n0 + j * 16 + cl;
#pragma unroll
                for (int reg = 0; reg < 4; reg++) {
                    int rr = row0 + m0 + i * 16 + quad * 4 + reg;
                    C[(size_t)rr * ldc + cc] = acc[i][j][reg] * alpha;
                }
            }
    }
}

__global__ __launch_bounds__(256) void k_gemm(
    const short* __restrict__ A, int lda,
    const short* __restrict__ B, int ldb,
    void* __restrict__ Cp, int ldc,
    int K, float alpha, const float* __restrict__ bias,
    long split_pitch, int out_mode)
{
    __shared__ __align__(16) short As[128 * 64];
    __shared__ __align__(16) short Bs[128 * 64];
    int kchunk = K / gridDim.z;
    gemm_body(As, Bs, A, lda, B, ldb, Cp, ldc,
              kchunk * blockIdx.z, kchunk * (blockIdx.z + 1), alpha, bias,
              (long)blockIdx.z * split_pitch, out_mode,
              blockIdx.y * 128, blockIdx.x * 128);
}

// ---------------- edgefeat body (device) ----------------
__device__ __forceinline__ void edgefeat_body(
    short* As, short* Bs, int row0,
    const short* __restrict__ Acat_in, const short* __restrict__ ajB,
    const short* __restrict__ liT, const short* __restrict__ ljT,
    const float* __restrict__ li_b, const float* __restrict__ lj_b,
    short* __restrict__ Acat)
{
    const int tid = threadIdx.x;
    const int wave = tid >> 6, lane = tid & 63;
    const int cl = lane & 15, quad = lane >> 4;
    const int m0 = (wave >> 1) * 64, n0 = (wave & 1) * 64;
    const int sr = lane >> 4, sc = (lane & 15) * 8;

    f32x4 ai_acc[4][4], aj_acc[4][4];
#pragma unroll
    for (int i = 0; i < 4; i++)
#pragma unroll
        for (int j = 0; j < 4; j++) {
            ai_acc[i][j] = (f32x4){0.f, 0.f, 0.f, 0.f};
            aj_acc[i][j] = (f32x4){0.f, 0.f, 0.f, 0.f};
        }

#pragma unroll
    for (int i = 0; i < 8; i++) {
        int r = wave * 32 + i * 4;
        gload16(Acat_in + (size_t)(row0 + r + sr) * KCAT + sc, As + r * 128);
        gload16(liT + (r + sr) * 128 + sc, Bs + r * 128);
    }
    __syncthreads();
#pragma unroll
    for (int kk = 0; kk < 128; kk += 32) {
        bf16x8 af[4], bf[4];
        int ko = kk + quad * 8;
#pragma unroll
        for (int i = 0; i < 4; i++) af[i] = *(const bf16x8*)(As + (m0 + i * 16 + cl) * 128 + ko);
#pragma unroll
        for (int j = 0; j < 4; j++) bf[j] = *(const bf16x8*)(Bs + (n0 + j * 16 + cl) * 128 + ko);
#pragma unroll
        for (int i = 0; i < 4; i++)
#pragma unroll
            for (int j = 0; j < 4; j++)
                ai_acc[i][j] = __builtin_amdgcn_mfma_f32_16x16x32_bf16(af[i], bf[j], ai_acc[i][j], 0, 0, 0);
    }
    __syncthreads();
#pragma unroll
    for (int i = 0; i < 8; i++) {
        int r = wave * 32 + i * 4;
        gload16(ajB + (size_t)(row0 + r + sr) * 128 + sc, As + r * 128);
        gload16(ljT + (r + sr) * 128 + sc, Bs + r * 128);
    }
    __syncthreads();
#pragma unroll
    for (int kk = 0; kk < 128; kk += 32) {
        bf16x8 af[4], bf[4];
        int ko = kk + quad * 8;
#pragma unroll
        for (int i = 0; i < 4; i++) af[i] = *(const bf16x8*)(As + (m0 + i * 16 + cl) * 128 + ko);
#pragma unroll
        for (int j = 0; j < 4; j++) bf[j] = *(const bf16x8*)(Bs + (n0 + j * 16 + cl) * 128 + ko);
#pragma unroll
        for (int i = 0; i < 4; i++)
#pragma unroll
            for (int j = 0; j < 4; j++)
                aj_acc[i][j] = __builtin_amdgcn_mfma_f32_16x16x32_bf16(af[i], bf[j], aj_acc[i][j], 0, 0, 0);
    }
#pragma unroll
    for (int i = 0; i < 4; i++)
#pragma unroll
        for (int j = 0; j < 4; j++) {
            int cc = n0 + j * 16 + cl;
            float bi = li_b[cc], bj = lj_b[cc];
#pragma unroll
            for (int reg = 0; reg < 4; reg++) {
                int rr = row0 + m0 + i * 16 + quad * 4 + reg;
                float hv = ai_acc[i][j][reg] + bi;
                float gv = aj_acc[i][j][reg] + bj;
                short* rowp = Acat + (size_t)rr * KCAT;
                rowp[128 + cc] = f2bf(hv + gv);
                rowp[256 + cc] = f2bf(hv - gv);
                rowp[384 + cc] = f2bf(hv * gv);
            }
        }
}

// ---------------- D2: edgefeat(32) + QK'(64) + W2T(5) + sortfin(1) ----------------
__global__ __launch_bounds__(256) void k_big(
    const short* __restrict__ Acat_in, const short* __restrict__ ajB,
    const short* __restrict__ liT, const short* __restrict__ ljT,
    const float* __restrict__ li_b, const float* __restrict__ lj_b,
    short* __restrict__ Acat,
    const short* __restrict__ embB, const short* __restrict__ WqkT,
    short* __restrict__ QKB,
    const short* __restrict__ olT, const short* __restrict__ BcatT,
    short* __restrict__ W2T,
    const int* __restrict__ cntS, const int* __restrict__ cntT,
    const int* __restrict__ srcO, const int* __restrict__ rankIn,
    const int* __restrict__ idxTP,
    const float* __restrict__ cwq4, const float* __restrict__ cwk4,
    float* __restrict__ cwq, float* __restrict__ cwk,
    int* __restrict__ segStart, int* __restrict__ segStartT,
    int* __restrict__ rankS, int* __restrict__ idxT, int* __restrict__ nsegp)
{
    __shared__ __align__(16) char smem[65536];
    if (blockIdx.x < 32) {
        edgefeat_body((short*)smem, (short*)(smem + 32768), blockIdx.x * 128,
                      Acat_in, ajB, liT, ljT, li_b, lj_b, Acat);
    } else if (blockIdx.x < 96) {
        int id = blockIdx.x - 32;
        gemm_body((short*)smem, (short*)(smem + 16384),
                  embB, H, WqkT, H, QKB, 2048, 0, H, 1.0f, nullptr, 0, 1,
                  (id >> 4) * 128, (id & 15) * 128);
    } else if (blockIdx.x < 101) {
        int id = blockIdx.x - 96;
        gemm_body((short*)smem, (short*)(smem + 16384),
                  olT, HH, BcatT, HH, W2T, 640, 0, HH, 1.0f, nullptr, 0, 1,
                  0, id * 128);
    } else {
        // sort finalize + cw reduce (~5 us, hidden under the GEMM blocks)
        int* sS = (int*)smem;            // 512 ints
        int* sT = sS + 512;              // 512 ints
        int* red = sT + 512;             // 256 ints
        const int t = threadIdx.x;
        // cw partial reduce: 4 j's per thread, 8 partials each
        for (int j = t; j < HH; j += 256) {
            cwq[j] = cwq4[j] + cwq4[1024 + j] + cwq4[2048 + j] + cwq4[3072 + j];
            cwk[j] = cwk4[j] + cwk4[1024 + j] + cwk4[2048 + j] + cwk4[3072 + j];
        }
        sS[t] = cntS[t]; sS[t + 256] = cntS[t + 256];
        sT[t] = cntT[t]; sT[t + 256] = cntT[t + 256];
        __syncthreads();
        for (int off = 1; off < 512; off <<= 1) {
            int i2 = t + 256;
            int a1 = (t >= off) ? sS[t - off] : 0;
            int b1 = (t >= off) ? sT[t - off] : 0;
            int a2 = sS[i2 - off];
            int b2 = sT[i2 - off];
            __syncthreads();
            sS[t] += a1; sT[t] += b1;
            sS[i2] += a2; sT[i2] += b2;
            __syncthreads();
        }
        segStart[t + 1]    = sS[t];
        segStart[t + 257]  = sS[t + 256];
        segStartT[t + 1]   = sT[t];
        segStartT[t + 257] = sT[t + 256];
        if (t == 0) { segStart[0] = 0; segStartT[0] = 0; }
        red[t] = (cntS[t] > 0) + (cntS[t + 256] > 0);
        __syncthreads();
        for (int off = 128; off > 0; off >>= 1) {
            if (t < off) red[t] += red[t + off];
            __syncthreads();
        }
        if (t == 0) nsegp[0] = red[0];
        // rankS[e] = exclusive_start(src) + rankIn[e]
        for (int e = t; e < NE; e += 256) {
            int s = srcO[e];
            rankS[e] = (sS[s] - cntS[s]) + rankIn[e];
        }
        // idxT compaction from padded per-tgt lists
        for (int n = t; n < N_NODES; n += 256) {
            int c = cntT[n];
            int base = sT[n] - c;
            const int* srcp = idxTP + n * TPAD;
            for (int j = 0; j < c; j++) idxT[base + j] = srcp[j];
        }
    }
}

// ---------------- D3: Z split-K (32) + GT(32) + wave-parallel p/q/s (16) ----------------
__global__ __launch_bounds__(256) void k_zr(
    const short* __restrict__ QKB,
    const float* __restrict__ cwq, const float* __restrict__ cwk,
    const short* __restrict__ Acat, const short* __restrict__ W2T,
    short* __restrict__ GT,
    float* __restrict__ Z, float* __restrict__ pv, float* __restrict__ qv,
    float* __restrict__ sv)
{
    __shared__ __align__(16) char smem[32768];
    if (blockIdx.x < 32) {
        // Z = Q@K' split into 2 K-slices
        int zs = blockIdx.x >> 4;       // K slice 0/1
        int tile = blockIdx.x & 15;
        gemm_body((short*)smem, (short*)(smem + 16384),
                  QKB, 2048, QKB + 1024, 2048, Z, N_NODES,
                  zs * 512, zs * 512 + 512, ALPHA, nullptr,
                  (long)zs * ((long)N_NODES * N_NODES), 0,
                  (tile >> 2) * 128, (tile & 3) * 128);
    } else if (blockIdx.x < 64) {
        int id = blockIdx.x - 32;
        gemm_body((short*)smem, (short*)(smem + 16384),
                  Acat, KCAT, W2T, 640, GT, NE, 0, KCAT, 1.0f, nullptr, 0, 3,
                  id * 128, 0);
    } else {
        int b = blockIdx.x - 64;
        int t = threadIdx.x;
        int wave = t >> 6, lane = t & 63;
        if (b == 0 && wave == 0) {
            float a = 0.0f;
            for (int j = lane; j < HH; j += 64) a += cwq[j] * cwk[j];
            for (int off = 32; off > 0; off >>= 1) a += __shfl_down(a, off);
            if (lane == 0) sv[0] = a;
        }
        for (int ni = 0; ni < 8; ni++) {
            int n = b * 32 + wave * 8 + ni;
            const short* qr = QKB + (size_t)n * 2048;
            float pa = 0.0f, qa = 0.0f;
            int j0 = lane * 16;
#pragma unroll
            for (int j = 0; j < 16; j++) {
                pa += bf2f(qr[j0 + j]) * cwk[j0 + j];
                qa += bf2f(qr[1024 + j0 + j]) * cwq[j0 + j];
            }
            for (int off = 32; off > 0; off >>= 1) {
                pa += __shfl_down(pa, off);
                qa += __shfl_down(qa, off);
            }
            if (lane == 0) { pv[n] = pa; qv[n] = qa; }
        }
    }
}

// ---------------- D4 denom (orig-edge rows) ----------------
// l[r,c] = (Z[tr,tc] + α·er·q[tc]) + ec·β,  β = α·(p_tr + er·s)
// row[] scattered by rankS so segment sums read contiguous LDS ranges.
__global__ __launch_bounds__(512) void k_denom(
    const float* __restrict__ Z, const float* __restrict__ pv,
    const float* __restrict__ qv, const float* __restrict__ sv,
    const int* __restrict__ tgtO, const float* __restrict__ ew,
    const int* __restrict__ rankS,
    const int* __restrict__ segStart, float* __restrict__ rDen)
{
    __shared__ float row[NE];        // 16 KB
    __shared__ float zq[N_NODES];    // 2 KB
    const int r = blockIdx.x, t = threadIdx.x;
    const int tr = tgtO[r];
    const float er = ew[r];
    const float aer = ALPHA * er;
    for (int i = t; i < N_NODES; i += 512)
        zq[i] = Z[(size_t)tr * N_NODES + i]
              + Z[(size_t)N_NODES * N_NODES + (size_t)tr * N_NODES + i]
              + aer * qv[i];
    __syncthreads();
    const float beta = ALPHA * (pv[tr] + er * sv[0]);
    for (int c = t; c < NE; c += 512)
        row[rankS[c]] = __expf(zq[tgtO[c]] + ew[c] * beta);
    __syncthreads();
    float* rd = rDen + (size_t)r * N_NODES;
    if (t < N_NODES) {
        int a = segStart[t], b = segStart[t + 1];
        float s = 0.0f;
        for (int p = a; p < b; p++) s += row[p];
        rd[t] = (s > 0.0f) ? 1.0f / s : 0.0f;
    }
}

// ---------------- D5 Pagg (orig-edge columns) ----------------
__global__ __launch_bounds__(256) void k_pagg2(
    const float* __restrict__ Z, const float* __restrict__ pv,
    const float* __restrict__ qv, const float* __restrict__ sv,
    const float* __restrict__ rDen,
    const int* __restrict__ tgtO, const float* __restrict__ ew,
    const int* __restrict__ srcO, const int* __restrict__ segStartT,
    const int* __restrict__ idxT, short* __restrict__ PaggB)
{
    __shared__ float zrow[N_NODES];   // 2 KB
    __shared__ float aq[N_NODES];     // 2 KB (alpha * q)
    __shared__ float erL[32];
    __shared__ int   eL[32];
    const int n = blockIdx.y;
    const int c0 = blockIdx.x * 1024;
    const int t = threadIdx.x;
    for (int i = t; i < N_NODES; i += 256) {
        zrow[i] = Z[(size_t)n * N_NODES + i]
                + Z[(size_t)N_NODES * N_NODES + (size_t)n * N_NODES + i];
        aq[i]   = ALPHA * qv[i];
    }
    __syncthreads();
    const float p_n = pv[n];
    const float s = sv[0];
    float A4[4], cB4[4];
    int sc4[4];
#pragma unroll
    for (int q = 0; q < 4; q++) {
        int c = c0 + t + q * 256;
        int tc = tgtO[c]; float ec = ew[c];
        A4[q]  = zrow[tc] + (ALPHA * ec) * p_n;
        cB4[q] = aq[tc] + (ALPHA * ec) * s;
        sc4[q] = srcO[c];
    }
    float acc[4] = {0.f, 0.f, 0.f, 0.f};
    const int a = segStartT[n], b = segStartT[n + 1];
    for (int ch = a; ch < b; ch += 32) {
        int ne = b - ch; if (ne > 32) ne = 32;
        __syncthreads();
        if (t < ne) { int e = idxT[ch + t]; eL[t] = e; erL[t] = ew[e]; }
        __syncthreads();
        for (int k = 0; k < ne; k++) {
            const float er = erL[k];
            const float* rde = rDen + (size_t)eL[k] * N_NODES;
#pragma unroll
            for (int q = 0; q < 4; q++)
                acc[q] += __expf(A4[q] + er * cB4[q]) * rde[sc4[q]];
        }
    }
    short* pr = PaggB + (size_t)n * NE + c0;
#pragma unroll
    for (int q = 0; q < 4; q++)
        pr[t + q * 256] = f2bf(acc[q]);
}

// ---------------- D7 head: sum 8 agg partials + LN + FFN + LN ----------------
__global__ __launch_bounds__(128) void k_head(
    const float* __restrict__ aggP, const int* __restrict__ segStartT,
    const int* __restrict__ nsegp,
    const float* __restrict__ cvec32, const float* __restrict__ ol_b,
    const float* __restrict__ ln_g, const float* __restrict__ ln_b,
    const float* __restrict__ f1_w, const float* __restrict__ f1_b,
    const float* __restrict__ f2_w, const float* __restrict__ f2_b,
    const float* __restrict__ f3_w, const float* __restrict__ f3_b,
    float* __restrict__ out)
{
    __shared__ float x[H];
    __shared__ float red[H];
    int t = threadIdx.x, row = blockIdx.x;
    int cnt = segStartT[row + 1] - segStartT[row];
    float cv = 0.0f;
#pragma unroll
    for (int z = 0; z < 32; z++) cv += cvec32[z * 128 + t];
    float v = (float)cnt * (ol_b[t] + (float)nsegp[0] * cv);
    const float* ap = aggP + (size_t)row * H + t;
#pragma unroll
    for (int z = 0; z < 8; z++) v += ap[(size_t)z * N_NODES * H];
    red[t] = v; __syncthreads();
    for (int s = 64; s > 0; s >>= 1) { if (t < s) red[t] += red[t + s]; __syncthreads(); }
    float mu = red[0] * (1.0f / H); __syncthreads();
    float dv = v - mu;
    red[t] = dv * dv; __syncthreads();
    for (int s = 64; s > 0; s >>= 1) { if (t < s) red[t] += red[t + s]; __syncthreads(); }
    float var = red[0] * (1.0f / H); __syncthreads();
    x[t] = dv * rsqrtf(var + 1e-5f) * ln_g[t] + ln_b[t];
    __syncthreads();
    const float* Ws[3] = { f1_w, f2_w, f3_w };
    const float* Bb[3] = { f1_b, f2_b, f3_b };
    for (int l = 0; l < 3; l++) {
        float acc = Bb[l][t];
        const float* Wl = Ws[l];
        for (int k = 0; k < H; k++) acc = fmaf(x[k], Wl[k * H + t], acc);
        float o = fmaxf(acc, 0.0f) + log1pf(expf(-fabsf(acc)));
        __syncthreads();
        x[t] = o;
        __syncthreads();
    }
    float xv = x[t];
    red[t] = xv; __syncthreads();
    for (int s = 64; s > 0; s >>= 1) { if (t < s) red[t] += red[t + s]; __syncthreads(); }
    mu = red[0] * (1.0f / H); __syncthreads();
    float dv2 = xv - mu;
    red[t] = dv2 * dv2; __syncthreads();
    for (int s = 64; s > 0; s >>= 1) { if (t < s) red[t] += red[t + s]; __syncthreads(); }
    var = red[0] * (1.0f / H);
    out[row * H + t] = dv2 * rsqrtf(var + 1e-5f) * ln_g[t] + ln_b[t];
}

// ---------------- launch ----------------

extern "C" void kernel_launch(void* const* d_in, const int* in_sizes, int n_in,
                              void* d_out, int out_size, void* d_ws, size_t ws_size,
                              hipStream_t stream) {
    const float* atom_embs   = (const float*)d_in[0];
    const float* pos         = (const float*)d_in[1];
    const float* edge_weight = (const float*)d_in[2];
    const int*   edge_idx    = (const int*)d_in[3];
    const float* Wq   = (const float*)d_in[4];
    const float* Wk   = (const float*)d_in[5];
    const float* Wv   = (const float*)d_in[6];
    const float* li_w = (const float*)d_in[7];
    const float* li_b = (const float*)d_in[8];
    const float* lj_w = (const float*)d_in[9];
    const float* lj_b = (const float*)d_in[10];
    const float* el_w = (const float*)d_in[11];
    const float* el_b = (const float*)d_in[12];
    const float* rl_w = (const float*)d_in[13];
    const float* rl_b = (const float*)d_in[14];
    const float* ol_w = (const float*)d_in[15];
    const float* ol_b = (const float*)d_in[16];
    const float* ln_g = (const float*)d_in[17];
    const float* ln_b = (const float*)d_in[18];
    const float* f1_w = (const float*)d_in[19];
    const float* f1_b = (const float*)d_in[20];
    const float* f2_w = (const float*)d_in[21];
    const float* f2_b = (const float*)d_in[22];
    const float* f3_w = (const float*)d_in[23];
    const float* f3_b = (const float*)d_in[24];
    float* out = (float*)d_out;

    char* w = (char*)d_ws;
    size_t off = 0;
    auto alloc = [&](size_t bytes) -> void* {
        void* p = w + off;
        off += (bytes + 255) & ~(size_t)255;
        return p;
    };
    int*   cntS      = (int*)alloc(2 * N_NODES * 4);   // cntS[512] + cntT[512], one memset
    int*   cntT      = cntS + N_NODES;
    int*   srcO      = (int*)alloc(NE * 4);
    int*   tgtO      = (int*)alloc(NE * 4);
    int*   rankIn    = (int*)alloc(NE * 4);
    int*   rankS     = (int*)alloc(NE * 4);
    int*   idxT      = (int*)alloc(NE * 4);
    int*   idxTP     = (int*)alloc((size_t)N_NODES * TPAD * 4);
    int*   segStart  = (int*)alloc((N_NODES + 1) * 4);
    int*   segStartT = (int*)alloc((N_NODES + 1) * 4);
    int*   nsegp     = (int*)alloc(4);
    short* Acat   = (short*)alloc((size_t)NE * KCAT * 2);
    short* ajB    = (short*)alloc((size_t)NE * H * 2);
    short* BcatT  = (short*)alloc((size_t)640 * HH * 2);
    short* WqkT   = (short*)alloc((size_t)2048 * H * 2);
    float* cwq4   = (float*)alloc(4 * HH * 4);
    float* cwk4   = (float*)alloc(4 * HH * 4);
    float* cwq    = (float*)alloc(HH * 4);
    float* cwk    = (float*)alloc(HH * 4);
    short* olT    = (short*)alloc((size_t)H * HH * 2);
    short* liT    = (short*)alloc((size_t)H * H * 2);
    short* ljT    = (short*)alloc((size_t)H * H * 2);
    short* embB   = (short*)alloc((size_t)N_NODES * H * 2);
    float* cvec32 = (float*)alloc(RF * 4);
    short* W2T    = (short*)alloc((size_t)H * 640 * 2);
    short* QKB    = (short*)alloc((size_t)N_NODES * 2048 * 2);
    float* Z      = (float*)alloc((size_t)2 * N_NODES * N_NODES * 4);  // 2 K-slices
    float* pv     = (float*)alloc(N_NODES * 4);
    float* qv     = (float*)alloc(N_NODES * 4);
    float* sv     = (float*)alloc(4);
    short* GT     = (short*)alloc((size_t)H * NE * 2);
    float* rDen   = (float*)alloc((size_t)NE * N_NODES * 4);
    short* PaggB  = (short*)alloc((size_t)N_NODES * NE * 2);
    float* aggP   = (float*)alloc((size_t)8 * N_NODES * H * 4);

    // D0: zero the atomic counters (4 KB)
    hipMemsetAsync(cntS, 0, 2 * N_NODES * 4, stream);
    // D1: prep (fully parallel; sort histograms via global atomics)
    k_prep<<<RTOT / 256, 256, 0, stream>>>(
        edge_idx, edge_weight, atom_embs, pos,
        Wq, Wk, Wv, li_w, lj_w, el_w, rl_w, ol_w, el_b, rl_b,
        srcO, tgtO, rankIn, cntS, cntT, idxTP,
        Acat, ajB, BcatT, WqkT, cwq4, cwk4, olT, liT, ljT, embB, cvec32);
    // D2: edgefeat + QK' + W2T + sort-finalize/cw-reduce block
    k_big<<<102, 256, 0, stream>>>(Acat, ajB, liT, ljT, li_b, lj_b, Acat,
                                   embB, WqkT, QKB, olT, BcatT, W2T,
                                   cntS, cntT, srcO, rankIn, idxTP,
                                   cwq4, cwk4, cwq, cwk,
                                   segStart, segStartT, rankS, idxT, nsegp);
    // D3: Z (split-K=2) + GT + wave-parallel p/q/s
    k_zr<<<80, 256, 0, stream>>>(QKB, cwq, cwk, Acat, W2T, GT, Z, pv, qv, sv);
    // D4: denominators (edge-parallel, 4096 blocks)
    k_denom<<<NE, 512, 0, stream>>>(Z, pv, qv, sv, tgtO, edge_weight, rankS,
                                    segStart, rDen);
    // D5: Pagg
    {
        dim3 g(4, N_NODES);
        k_pagg2<<<g, 256, 0, stream>>>(Z, pv, qv, sv, rDen, tgtO, edge_weight,
                                       srcO, segStartT, idxT, PaggB);
    }
    // D6: agg = Pagg @ G : split-K=8
    {
        dim3 g(1, N_NODES / 128, 8);
        k_gemm<<<g, 256, 0, stream>>>(PaggB, NE, GT, NE, aggP, H, NE, 1.0f, nullptr,
                                      (long)N_NODES * H, 0);
    }
    // D7: head
    k_head<<<N_NODES, 128, 0, stream>>>(aggP, segStartT, nsegp, cvec32, ol_b,
                                        ln_g, ln_b, f1_w, f1_b, f2_w, f2_b, f3_w, f3_b, out);
}